// Round 5
// baseline (371.883 us; speedup 1.0000x reference)
//
#include <hip/hip_runtime.h>
#include <hip/hip_bf16.h>
#include <hip/hip_fp16.h>

// ---------------------------------------------------------------------------
// FakeQuantLinear (Q4_K_M fake-quant + GEMM): out = x @ fq(W)^T + bias
// R5: GEMM block tile 256x256, 4 waves, wave tile 128x128 (8x8 MFMA
//     16x16x32, acc=256 VGPRs, 1 wave/SIMD). LDS fragment traffic per
//     output drops 1.5x vs R4 -> MFMA becomes the binding pipe (model:
//     MFMA 66us vs LDS 55us). Double-buffer (2x32KB) now load-bearing:
//     no TLP at 1 wave/SIMD, prefetch hides behind 1240-cyc compute phase.
//     Proven XOR LDS swizzle + 16x16x32 fragments unchanged.
// ---------------------------------------------------------------------------

typedef __attribute__((ext_vector_type(8))) short bf16x8;    // 8 bf16 = 4 VGPRs
typedef __attribute__((ext_vector_type(8))) unsigned short ushort8;
typedef __attribute__((ext_vector_type(4))) float f32x4;     // MFMA acc

__device__ __forceinline__ unsigned short f2bf(float f) {
  unsigned int u = __float_as_uint(f);
  u += 0x7fffu + ((u >> 16) & 1u);
  return (unsigned short)(u >> 16);
}

// ---------------------------------------------------------------------------
// Fused prep kernel (unchanged from R4 — best residual so far).
// Blocks [0, castBlocks): cast x -> bf16, 8 elems/thread.
// Blocks [castBlocks, ..): Q4_K_M fake-quant W -> bf16, 4 elems/lane,
//   1 wave per 256-elem superblock (coalesced 16 B/lane).
// ---------------------------------------------------------------------------
__global__ __launch_bounds__(256) void prep_kernel(
    const float* __restrict__ x, unsigned short* __restrict__ xb,
    const float* __restrict__ w, unsigned short* __restrict__ wq,
    int castBlocks) {
  if ((int)blockIdx.x < castBlocks) {
    const size_t i = ((size_t)blockIdx.x * 256 + threadIdx.x) * 8;
    const float4 a = *(const float4*)(x + i);
    const float4 b = *(const float4*)(x + i + 4);
    ushort8 o = {f2bf(a.x), f2bf(a.y), f2bf(a.z), f2bf(a.w),
                 f2bf(b.x), f2bf(b.y), f2bf(b.z), f2bf(b.w)};
    *(ushort8*)(xb + i) = o;
    return;
  }
  const int qb   = blockIdx.x - castBlocks;
  const int lane = threadIdx.x & 63;
  const int wv   = threadIdx.x >> 6;
  const size_t base = (((size_t)qb * 4 + wv) * 256) + (size_t)lane * 4;
  const float4 v = *(const float4*)(w + base);

  float mn = fminf(fminf(v.x, v.y), fminf(v.z, v.w));
  float mx = fmaxf(fmaxf(v.x, v.y), fmaxf(v.z, v.w));
#pragma unroll
  for (int off = 1; off <= 4; off <<= 1) {
    mn = fminf(mn, __shfl_xor(mn, off));
    mx = fmaxf(mx, __shfl_xor(mx, off));
  }
  const float sub_min = fminf(mn, 0.0f);
  const float sub_max = fmaxf(mx, 0.0f);
  const float scale_raw = fmaxf(sub_max - sub_min, 1e-8f) / 15.0f;

  float smn = scale_raw, smx = scale_raw, supermin = sub_min;
#pragma unroll
  for (int off = 8; off <= 32; off <<= 1) {
    smn = fminf(smn, __shfl_xor(smn, off));
    smx = fmaxf(smx, __shfl_xor(smx, off));
    supermin = fminf(supermin, __shfl_xor(supermin, off));
  }
  const float s_range = fmaxf(smx - smn, 1e-8f);
  float s_int = rintf((scale_raw - smn) / s_range * 63.0f);
  s_int = fminf(fmaxf(s_int, 0.0f), 63.0f);
  float scale = s_int / 63.0f * s_range + smn;
  scale = fmaxf(scale, 1e-8f);
  const float inv_scale = 1.0f / scale;

  const float sm  = __half2float(__float2half(supermin));
  const float adj = sub_min - sm;

  float e[4] = {v.x, v.y, v.z, v.w};
  ushort4 o;
  unsigned short* op = (unsigned short*)&o;
#pragma unroll
  for (int k = 0; k < 4; ++k) {
    const float t = (e[k] - sm) - adj;
    float qv = rintf(t * inv_scale);
    qv = fminf(fmaxf(qv, 0.0f), 15.0f);
    op[k] = f2bf((qv * scale + adj) + sm);
  }
  *(ushort4*)(wq + base) = o;
}

// ---------------------------------------------------------------------------
// bf16 MFMA GEMM, C[m,n] = sum_k A[m,k]*B[n,k] + bias[n]
// Block tile 256x256, BK=32; 4 waves (2x2); wave tile 128x128 = 8x8 MFMA
// 16x16x32. Double-buffered LDS (2 x 32 KiB), one barrier/iter, prefetch
// distance 1. XOR k-chunk swizzle -> zero bank conflicts (verified R2-R4).
// ---------------------------------------------------------------------------
#define BM 256
#define BN 256
#define BK 32

__device__ __forceinline__ void async_cp16(void* lds, const void* g) {
  __builtin_amdgcn_global_load_lds(
      (__attribute__((address_space(1))) void*)(void*)g,
      (__attribute__((address_space(3))) void*)lds, 16, 0, 0);
}

__global__ __launch_bounds__(256, 1) void gemm_bt_kernel(
    const unsigned short* __restrict__ A,   // [M][K] bf16 bits
    const unsigned short* __restrict__ B,   // [N][K] bf16 bits (fq weight)
    const float* __restrict__ bias,         // [N]
    float* __restrict__ C,                  // [M][N] f32
    int M, int N, int K) {
  __shared__ unsigned short lds_a[2][BM * BK];   // 2 x 16 KiB
  __shared__ unsigned short lds_b[2][BN * BK];   // 2 x 16 KiB

  const int tid  = threadIdx.x;
  const int lane = tid & 63;
  const int wv   = tid >> 6;
  const int wm   = wv >> 1;          // wave row (128 rows)
  const int wn   = wv & 1;           // wave col (128 cols)
  const int bx   = blockIdx.x;       // N tile (256)
  const int by   = blockIdx.y;       // M tile (256)

  // staging: thread t -> row t>>2 (+64k), slot t&3; fetch chunk (t&3)^((t>>3)&3)
  const int r0   = tid >> 2;
  const int cw   = (tid & 3) ^ ((tid >> 3) & 3);
  const int koff = cw * 8;

  const unsigned short* ga0 = A + (size_t)(by * BM + r0)       * K + koff;
  const unsigned short* ga1 = A + (size_t)(by * BM + r0 + 64)  * K + koff;
  const unsigned short* ga2 = A + (size_t)(by * BM + r0 + 128) * K + koff;
  const unsigned short* ga3 = A + (size_t)(by * BM + r0 + 192) * K + koff;
  const unsigned short* gb0 = B + (size_t)(bx * BN + r0)       * K + koff;
  const unsigned short* gb1 = B + (size_t)(bx * BN + r0 + 64)  * K + koff;
  const unsigned short* gb2 = B + (size_t)(bx * BN + r0 + 128) * K + koff;
  const unsigned short* gb3 = B + (size_t)(bx * BN + r0 + 192) * K + koff;

  const int lo0 = tid * 8, lo1 = (tid + 256) * 8,
            lo2 = (tid + 512) * 8, lo3 = (tid + 768) * 8;

  f32x4 acc[8][8] = {};

  // fragment addressing: m/n = lane&15, k-chunk = lane>>4, XOR-swizzled slot
  const int arow  = wm * 128 + (lane & 15);
  const int brow  = wn * 128 + (lane & 15);
  const int kslot = (((lane >> 4) ^ ((lane >> 1) & 3))) * 8;

  // prefetch tile 0 into buffer 0
  async_cp16(lds_a[0] + lo0, ga0);
  async_cp16(lds_a[0] + lo1, ga1);
  async_cp16(lds_a[0] + lo2, ga2);
  async_cp16(lds_a[0] + lo3, ga3);
  async_cp16(lds_b[0] + lo0, gb0);
  async_cp16(lds_b[0] + lo1, gb1);
  async_cp16(lds_b[0] + lo2, gb2);
  async_cp16(lds_b[0] + lo3, gb3);

  for (int k0 = 0; k0 < K; k0 += BK) {
    const int cur = (k0 >> 5) & 1;
    __syncthreads();   // drains prefetch for buf[cur]
    if (k0 + BK < K) {
      const int nxt = cur ^ 1;
      const int kn  = k0 + BK;
      async_cp16(lds_a[nxt] + lo0, ga0 + kn);
      async_cp16(lds_a[nxt] + lo1, ga1 + kn);
      async_cp16(lds_a[nxt] + lo2, ga2 + kn);
      async_cp16(lds_a[nxt] + lo3, ga3 + kn);
      async_cp16(lds_b[nxt] + lo0, gb0 + kn);
      async_cp16(lds_b[nxt] + lo1, gb1 + kn);
      async_cp16(lds_b[nxt] + lo2, gb2 + kn);
      async_cp16(lds_b[nxt] + lo3, gb3 + kn);
    }

    bf16x8 af[8], bfr[8];
#pragma unroll
    for (int i = 0; i < 8; ++i)
      af[i] = *(const bf16x8*)(lds_a[cur] + (arow + i * 16) * BK + kslot);
#pragma unroll
    for (int j = 0; j < 8; ++j)
      bfr[j] = *(const bf16x8*)(lds_b[cur] + (brow + j * 16) * BK + kslot);

#pragma unroll
    for (int i = 0; i < 8; ++i)
#pragma unroll
      for (int j = 0; j < 8; ++j)
        acc[i][j] = __builtin_amdgcn_mfma_f32_16x16x32_bf16(af[i], bfr[j],
                                                            acc[i][j], 0, 0, 0);
  }

  // Epilogue. C/D layout: col = lane&15, row = (lane>>4)*4 + reg
  const int rbase = by * BM + wm * 128 + (lane >> 4) * 4;
  const int cbase = bx * BN + wn * 128 + (lane & 15);
#pragma unroll
  for (int j = 0; j < 8; ++j) {
    const int c = cbase + j * 16;
    const float bv = bias[c];
#pragma unroll
    for (int i = 0; i < 8; ++i) {
#pragma unroll
      for (int r = 0; r < 4; ++r) {
        C[(size_t)(rbase + i * 16 + r) * N + c] = acc[i][j][r] + bv;
      }
    }
  }
}

// ---------------------------------------------------------------------------
extern "C" void kernel_launch(void* const* d_in, const int* in_sizes, int n_in,
                              void* d_out, int out_size, void* d_ws, size_t ws_size,
                              hipStream_t stream) {
  const float* x    = (const float*)d_in[0];
  const float* w    = (const float*)d_in[1];
  const float* bias = (const float*)d_in[2];
  float* out = (float*)d_out;

  const long long xn = in_sizes[0];   // M*K
  const long long wn = in_sizes[1];   // N*K
  const int N = in_sizes[2];
  const int K = (int)(wn / N);
  const int M = (int)(xn / K);

  unsigned short* xb = (unsigned short*)d_ws;
  unsigned short* wb = xb + (size_t)M * K;

  const int castBlocks  = (int)(xn / (256 * 8));    // 8 elems/thread
  const int quantBlocks = (int)(wn / (256 * 4));    // 1024 elems/block
  prep_kernel<<<castBlocks + quantBlocks, 256, 0, stream>>>(x, xb, w, wb,
                                                            castBlocks);
  gemm_bt_kernel<<<dim3(N / BN, M / BM), 256, 0, stream>>>(xb, wb, bias, out,
                                                           M, N, K);
}

// Round 6
// 288.950 us; speedup vs baseline: 1.2870x; 1.2870x over previous
//
#include <hip/hip_runtime.h>
#include <hip/hip_bf16.h>
#include <hip/hip_fp16.h>

// ---------------------------------------------------------------------------
// FakeQuantLinear (Q4_K_M fake-quant + GEMM): out = x @ fq(W)^T + bias
// R6: revert to R4's 256x128 tile / 8 waves/CU (R5's 1 wave/SIMD exposed all
//     latency: 221us). New lever: BK=64 single-buffered -> 64 K-iters instead
//     of 128, halving the per-iter barrier-drain fixed cost. LDS swizzle
//     extended to 8 chunks/row: slot s of row r holds chunk s^(r&7).
// ---------------------------------------------------------------------------

typedef __attribute__((ext_vector_type(8))) short bf16x8;    // 8 bf16 = 4 VGPRs
typedef __attribute__((ext_vector_type(8))) unsigned short ushort8;
typedef __attribute__((ext_vector_type(4))) float f32x4;     // MFMA acc

__device__ __forceinline__ unsigned short f2bf(float f) {
  unsigned int u = __float_as_uint(f);
  u += 0x7fffu + ((u >> 16) & 1u);
  return (unsigned short)(u >> 16);
}

// ---------------------------------------------------------------------------
// Fused prep kernel (unchanged from R4).
// ---------------------------------------------------------------------------
__global__ __launch_bounds__(256) void prep_kernel(
    const float* __restrict__ x, unsigned short* __restrict__ xb,
    const float* __restrict__ w, unsigned short* __restrict__ wq,
    int castBlocks) {
  if ((int)blockIdx.x < castBlocks) {
    const size_t i = ((size_t)blockIdx.x * 256 + threadIdx.x) * 8;
    const float4 a = *(const float4*)(x + i);
    const float4 b = *(const float4*)(x + i + 4);
    ushort8 o = {f2bf(a.x), f2bf(a.y), f2bf(a.z), f2bf(a.w),
                 f2bf(b.x), f2bf(b.y), f2bf(b.z), f2bf(b.w)};
    *(ushort8*)(xb + i) = o;
    return;
  }
  const int qb   = blockIdx.x - castBlocks;
  const int lane = threadIdx.x & 63;
  const int wv   = threadIdx.x >> 6;
  const size_t base = (((size_t)qb * 4 + wv) * 256) + (size_t)lane * 4;
  const float4 v = *(const float4*)(w + base);

  float mn = fminf(fminf(v.x, v.y), fminf(v.z, v.w));
  float mx = fmaxf(fmaxf(v.x, v.y), fmaxf(v.z, v.w));
#pragma unroll
  for (int off = 1; off <= 4; off <<= 1) {
    mn = fminf(mn, __shfl_xor(mn, off));
    mx = fmaxf(mx, __shfl_xor(mx, off));
  }
  const float sub_min = fminf(mn, 0.0f);
  const float sub_max = fmaxf(mx, 0.0f);
  const float scale_raw = fmaxf(sub_max - sub_min, 1e-8f) / 15.0f;

  float smn = scale_raw, smx = scale_raw, supermin = sub_min;
#pragma unroll
  for (int off = 8; off <= 32; off <<= 1) {
    smn = fminf(smn, __shfl_xor(smn, off));
    smx = fmaxf(smx, __shfl_xor(smx, off));
    supermin = fminf(supermin, __shfl_xor(supermin, off));
  }
  const float s_range = fmaxf(smx - smn, 1e-8f);
  float s_int = rintf((scale_raw - smn) / s_range * 63.0f);
  s_int = fminf(fmaxf(s_int, 0.0f), 63.0f);
  float scale = s_int / 63.0f * s_range + smn;
  scale = fmaxf(scale, 1e-8f);
  const float inv_scale = 1.0f / scale;

  const float sm  = __half2float(__float2half(supermin));
  const float adj = sub_min - sm;

  float e[4] = {v.x, v.y, v.z, v.w};
  ushort4 o;
  unsigned short* op = (unsigned short*)&o;
#pragma unroll
  for (int k = 0; k < 4; ++k) {
    const float t = (e[k] - sm) - adj;
    float qv = rintf(t * inv_scale);
    qv = fminf(fmaxf(qv, 0.0f), 15.0f);
    op[k] = f2bf((qv * scale + adj) + sm);
  }
  *(ushort4*)(wq + base) = o;
}

// ---------------------------------------------------------------------------
// bf16 MFMA GEMM, C[m,n] = sum_k A[m,k]*B[n,k] + bias[n]
// Block tile 256x128, BK=64, single-buffered; 4 waves (2x2); wave tile
// 128x64 = 8x4 MFMA 16x16x32 per 32-k half (64 MFMA/wave/iter).
// LDS rows = 64 ushorts = 8x16B chunks; slot s of row r holds global chunk
// s^(r&7) -> readers spread over all 8 bank-groups 2-way (conflict-free).
// ---------------------------------------------------------------------------
#define BM 256
#define BN 128
#define BK 64

__device__ __forceinline__ void async_cp16(void* lds, const void* g) {
  __builtin_amdgcn_global_load_lds(
      (__attribute__((address_space(1))) void*)(void*)g,
      (__attribute__((address_space(3))) void*)lds, 16, 0, 0);
}

__global__ __launch_bounds__(256, 2) void gemm_bt_kernel(
    const unsigned short* __restrict__ A,   // [M][K] bf16 bits
    const unsigned short* __restrict__ B,   // [N][K] bf16 bits (fq weight)
    const float* __restrict__ bias,         // [N]
    float* __restrict__ C,                  // [M][N] f32
    int M, int N, int K) {
  __shared__ unsigned short lds_a[BM * BK];   // 32 KiB
  __shared__ unsigned short lds_b[BN * BK];   // 16 KiB

  const int tid  = threadIdx.x;
  const int lane = tid & 63;
  const int wv   = tid >> 6;
  const int wm   = wv >> 1;          // wave row (128 rows each)
  const int wn   = wv & 1;           // wave col (64 cols each)
  const int bx   = blockIdx.x;       // N tile (128)
  const int by   = blockIdx.y;       // M tile (256)

  // staging: issue j covers rows j*32..j*32+31. Thread t -> row j*32+(t>>3),
  // slot t&7 (LDS offset = j*2048 + t*8 ushorts = uniform base + lane*16B).
  // Fetch global chunk (t&7)^((t>>3)&7) so slot s of row r holds s^(r&7).
  const int rloc = tid >> 3;                       // 0..31
  const int csw  = (tid & 7) ^ (rloc & 7);         // swizzled chunk
  const int koff = csw * 8;                        // ushort offset in row

  const unsigned short* gA[8];
  const unsigned short* gB[4];
#pragma unroll
  for (int j = 0; j < 8; ++j)
    gA[j] = A + (size_t)(by * BM + j * 32 + rloc) * K + koff;
#pragma unroll
  for (int j = 0; j < 4; ++j)
    gB[j] = B + (size_t)(bx * BN + j * 32 + rloc) * K + koff;

  f32x4 acc[8][4] = {};

  // fragment addressing: m/n = lane&15; k-chunk q = (lane>>4) + 4*half;
  // stored at slot q^(lane&7) (row&7 == lane&7 for all rows we touch).
  const int arow   = wm * 128 + (lane & 15);
  const int brow   = wn * 64 + (lane & 15);
  const int kslot0 = (((lane >> 4) ^ (lane & 7))) * 8;   // half 0
  const int kslot1 = kslot0 ^ 32;                        // half 1 (chunk+4)

  for (int k0 = 0; k0 < K; k0 += BK) {
#pragma unroll
    for (int j = 0; j < 8; ++j)
      async_cp16(lds_a + j * 2048 + tid * 8, gA[j] + k0);
#pragma unroll
    for (int j = 0; j < 4; ++j)
      async_cp16(lds_b + j * 2048 + tid * 8, gB[j] + k0);
    __syncthreads();   // drain staging

#pragma unroll
    for (int h = 0; h < 2; ++h) {
      const int ks = h ? kslot1 : kslot0;
      bf16x8 af[8], bfr[4];
#pragma unroll
      for (int i = 0; i < 8; ++i)
        af[i] = *(const bf16x8*)(lds_a + (arow + i * 16) * BK + ks);
#pragma unroll
      for (int j = 0; j < 4; ++j)
        bfr[j] = *(const bf16x8*)(lds_b + (brow + j * 16) * BK + ks);

#pragma unroll
      for (int i = 0; i < 8; ++i)
#pragma unroll
        for (int j = 0; j < 4; ++j)
          acc[i][j] = __builtin_amdgcn_mfma_f32_16x16x32_bf16(af[i], bfr[j],
                                                              acc[i][j], 0, 0, 0);
    }
    __syncthreads();   // protect LDS before next stage
  }

  // Epilogue. C/D layout: col = lane&15, row = (lane>>4)*4 + reg
  const int rbase = by * BM + wm * 128 + (lane >> 4) * 4;
  const int cbase = bx * BN + wn * 64 + (lane & 15);
#pragma unroll
  for (int j = 0; j < 4; ++j) {
    const int c = cbase + j * 16;
    const float bv = bias[c];
#pragma unroll
    for (int i = 0; i < 8; ++i) {
#pragma unroll
      for (int r = 0; r < 4; ++r) {
        C[(size_t)(rbase + i * 16 + r) * N + c] = acc[i][j][r] + bv;
      }
    }
  }
}

// ---------------------------------------------------------------------------
extern "C" void kernel_launch(void* const* d_in, const int* in_sizes, int n_in,
                              void* d_out, int out_size, void* d_ws, size_t ws_size,
                              hipStream_t stream) {
  const float* x    = (const float*)d_in[0];
  const float* w    = (const float*)d_in[1];
  const float* bias = (const float*)d_in[2];
  float* out = (float*)d_out;

  const long long xn = in_sizes[0];   // M*K
  const long long wn = in_sizes[1];   // N*K
  const int N = in_sizes[2];
  const int K = (int)(wn / N);
  const int M = (int)(xn / K);

  unsigned short* xb = (unsigned short*)d_ws;
  unsigned short* wb = xb + (size_t)M * K;

  const int castBlocks  = (int)(xn / (256 * 8));    // 8 elems/thread
  const int quantBlocks = (int)(wn / (256 * 4));    // 1024 elems/block
  prep_kernel<<<castBlocks + quantBlocks, 256, 0, stream>>>(x, xb, w, wb,
                                                            castBlocks);
  gemm_bt_kernel<<<dim3(N / BN, M / BM), 256, 0, stream>>>(xb, wb, bias, out,
                                                           M, N, K);
}